// Round 7
// baseline (1597.410 us; speedup 1.0000x reference)
//
#include <hip/hip_runtime.h>

#define NF 64
#define NH 32
#define NK 16
#define BLOCK 512
#define NWAVES (BLOCK / 64)

// Occupancy pinned to EXACTLY 4 waves/EU. Confirmed compiler pattern (R2/R3/R6):
// any range allowing 8 waves/EU makes the allocator shrink to 64 VGPRs and
// spill ~100 live floats -> GBs of scratch traffic (R6: 4.0 GB HBM, 1350 us).
// (4,4): budget 128 VGPRs, no incentive to shrink (occupancy capped at 4).
// Weights stay in global: after the block sort, their addresses are
// wave-uniform -> one L1 transaction broadcast per float4. LDS = 2.3 KB.

__global__ __attribute__((amdgpu_flat_work_group_size(BLOCK, BLOCK),
                          amdgpu_waves_per_eu(4, 4)))
void tree_mlp_kernel(
    const float* __restrict__ x,
    const float* __restrict__ W1, const float* __restrict__ b1,
    const float* __restrict__ W2, const float* __restrict__ b2,
    const float* __restrict__ W3, const float* __restrict__ b3,
    const float* __restrict__ leaf_best, const int* __restrict__ subset_idx,
    float* __restrict__ out, int N)
{
    __shared__ unsigned permL[BLOCK];   // 2048 B
    __shared__ int      sortL[64];      // 256 B  (nb*NWAVES <= 64)

    const int tid  = threadIdx.x;
    const int lane = tid & 63;
    const int wv   = tid >> 6;

    const int s = blockIdx.x * BLOCK + tid;
    int valid = (s < N) ? 1 : 0;
    int id    = valid ? s : 0;          // invalid lanes shadow sample 0, stay live
    int loc = 0, off = 0;

    #pragma unroll 1                    // keep level loop rolled (I$); body ~1.6k FMAs
    for (int level = 0; level < 4; ++level) {
        if (level > 0) {
            // ---- in-block counting sort by loc (ballot-based) ----
            const int nb = 1 << level;
            int myrank = 0;
            #pragma unroll 1
            for (int b = 0; b < nb; ++b) {
                const unsigned long long m = __ballot(loc == b);
                if (loc == b)
                    myrank = __popcll(m & ((1ull << lane) - 1ull));
                if (lane == 0)
                    sortL[b * NWAVES + wv] = (int)__popcll(m);
            }
            __syncthreads();
            // wave-parallel exclusive prefix over (bucket, wave)
            if (wv == 0) {
                const int mcnt = nb * NWAVES;
                const int cnt = (lane < mcnt) ? sortL[lane] : 0;
                int v = cnt;
                #pragma unroll
                for (int d = 1; d < 64; d <<= 1) {
                    const int t = __shfl_up(v, d);
                    if (lane >= d) v += t;
                }
                if (lane < mcnt) sortL[lane] = v - cnt;
            }
            __syncthreads();
            const int slot = sortL[loc * NWAVES + wv] + myrank;
            permL[slot] = ((unsigned)id << 5) | ((unsigned)valid << 4) | (unsigned)loc;
            __syncthreads();
            const unsigned p = permL[tid];
            id    = (int)(p >> 5);
            valid = (int)((p >> 4) & 1u);
            loc   = (int)(p & 15u);
            // sortL reuse is safe: next write is beyond the next __syncthreads
        }

        const int node = off + loc;     // wave-uniform after sort (boundary waves <=2 nodes)
        const float* xr = x + (size_t)id * NF;

        // Gather 16 subset features (the only scattered loads in the kernel)
        float xs[NK];
        const int* si = subset_idx + node * NK;
        #pragma unroll
        for (int k = 0; k < NK; ++k) xs[k] = xr[si[k]];

        // h1 = leaky(W1[node] @ xs + b1)   (32x16 GEMV, uniform-address float4)
        float h1v[NH];
        const float4* w1g = (const float4*)(W1 + node * (NH * NK));
        const float* b1g = b1 + node * NH;
        #pragma unroll
        for (int j = 0; j < NH; ++j) {
            float acc = b1g[j];
            #pragma unroll
            for (int q = 0; q < NK / 4; ++q) {
                const float4 t = w1g[j * 4 + q];
                acc += t.x * xs[q * 4 + 0];
                acc += t.y * xs[q * 4 + 1];
                acc += t.z * xs[q * 4 + 2];
                acc += t.w * xs[q * 4 + 3];
            }
            h1v[j] = (acc >= 0.f) ? acc : 0.01f * acc;
        }

        // h2 = leaky(W2[node] @ h1 + b2)   (32x32 GEMV, uniform-address float4)
        float h2v[NH];
        const float4* w2g = (const float4*)(W2 + node * (NH * NH));
        const float* b2g = b2 + node * NH;
        #pragma unroll
        for (int g = 0; g < NH; ++g) {
            float acc = b2g[g];
            #pragma unroll
            for (int q = 0; q < NH / 4; ++q) {
                const float4 t = w2g[g * 8 + q];
                acc += t.x * h1v[q * 4 + 0];
                acc += t.y * h1v[q * 4 + 1];
                acc += t.z * h1v[q * 4 + 2];
                acc += t.w * h1v[q * 4 + 3];
            }
            h2v[g] = (acc >= 0.f) ? acc : 0.01f * acc;
        }

        // logits; p0 < 0.5  <=>  l0 < l1  (softmax is monotone)
        const float4* w3g = (const float4*)(W3 + node * 2 * NH);
        float l0 = b3[node * 2 + 0];
        float l1 = b3[node * 2 + 1];
        #pragma unroll
        for (int q = 0; q < NH / 4; ++q) {
            const float4 t0 = w3g[q];
            l0 += t0.x * h2v[q * 4 + 0];
            l0 += t0.y * h2v[q * 4 + 1];
            l0 += t0.z * h2v[q * 4 + 2];
            l0 += t0.w * h2v[q * 4 + 3];
        }
        #pragma unroll
        for (int q = 0; q < NH / 4; ++q) {
            const float4 t1 = w3g[8 + q];
            l1 += t1.x * h2v[q * 4 + 0];
            l1 += t1.y * h2v[q * 4 + 1];
            l1 += t1.z * h2v[q * 4 + 2];
            l1 += t1.w * h2v[q * 4 + 3];
        }

        const int bit = (l0 < l1) ? 1 : 0;
        loc = 2 * loc + bit;
        off = 2 * off + 1;              // node offsets: 0, 1, 3, 7
    }

    if (valid) out[id] = leaf_best[loc];
}

extern "C" void kernel_launch(void* const* d_in, const int* in_sizes, int n_in,
                              void* d_out, int out_size, void* d_ws, size_t ws_size,
                              hipStream_t stream) {
    const float* x         = (const float*)d_in[0];
    const float* W1        = (const float*)d_in[1];
    const float* b1        = (const float*)d_in[2];
    const float* W2        = (const float*)d_in[3];
    const float* b2        = (const float*)d_in[4];
    const float* W3        = (const float*)d_in[5];
    const float* b3        = (const float*)d_in[6];
    const float* leaf_best = (const float*)d_in[7];
    const int*   subset    = (const int*)d_in[8];

    const int N = in_sizes[0] / NF;
    const int grid = (N + BLOCK - 1) / BLOCK;
    tree_mlp_kernel<<<grid, BLOCK, 0, stream>>>(
        x, W1, b1, W2, b2, W3, b3, leaf_best, subset, (float*)d_out, N);
}

// Round 8
// 629.482 us; speedup vs baseline: 2.5377x; 2.5377x over previous
//
#include <hip/hip_runtime.h>

#define NF 64
#define NH 32
#define NK 16
#define BLOCK 512
#define NWAVES (BLOCK / 64)

// Lesson R2/R3/R6/R7: occupancy attributes do NOT reliably raise the VGPR
// budget on this toolchain — every small-LDS build got 64 VGPRs + scratch
// spill (2-4 GB HBM traffic). Fix: fit IN 64 VGPRs. h2v[32] is eliminated by
// fusing the W3 logit accumulation into the h2 loop (each h2[g] dies at
// birth). Peak live ~56 floats (xs16 + h1v32 + temps) -> no spill, and the
// compiler's preferred 8 waves/EU becomes a latency-hiding win. Accumulation
// order is unchanged (g = 0..31 sequential) -> bit-exact vs R6.

__global__ __attribute__((amdgpu_flat_work_group_size(BLOCK, BLOCK)))
void tree_mlp_kernel(
    const float* __restrict__ x,
    const float* __restrict__ W1, const float* __restrict__ b1,
    const float* __restrict__ W2, const float* __restrict__ b2,
    const float* __restrict__ W3, const float* __restrict__ b3,
    const float* __restrict__ leaf_best, const int* __restrict__ subset_idx,
    float* __restrict__ out, int N)
{
    __shared__ unsigned permL[BLOCK];   // 2048 B
    __shared__ int      sortL[64];      // 256 B  (nb*NWAVES <= 64)

    const int tid  = threadIdx.x;
    const int lane = tid & 63;
    const int wv   = tid >> 6;

    const int s = blockIdx.x * BLOCK + tid;
    int valid = (s < N) ? 1 : 0;
    int id    = valid ? s : 0;          // invalid lanes shadow sample 0, stay live
    int loc = 0, off = 0;

    #pragma unroll 1                    // keep level loop rolled (I$)
    for (int level = 0; level < 4; ++level) {
        if (level > 0) {
            // ---- in-block counting sort by loc (ballot-based) ----
            const int nb = 1 << level;
            int myrank = 0;
            #pragma unroll 1
            for (int b = 0; b < nb; ++b) {
                const unsigned long long m = __ballot(loc == b);
                if (loc == b)
                    myrank = __popcll(m & ((1ull << lane) - 1ull));
                if (lane == 0)
                    sortL[b * NWAVES + wv] = (int)__popcll(m);
            }
            __syncthreads();
            // wave-parallel exclusive prefix over (bucket, wave)
            if (wv == 0) {
                const int mcnt = nb * NWAVES;
                const int cnt = (lane < mcnt) ? sortL[lane] : 0;
                int v = cnt;
                #pragma unroll
                for (int d = 1; d < 64; d <<= 1) {
                    const int t = __shfl_up(v, d);
                    if (lane >= d) v += t;
                }
                if (lane < mcnt) sortL[lane] = v - cnt;
            }
            __syncthreads();
            const int slot = sortL[loc * NWAVES + wv] + myrank;
            permL[slot] = ((unsigned)id << 5) | ((unsigned)valid << 4) | (unsigned)loc;
            __syncthreads();
            const unsigned p = permL[tid];
            id    = (int)(p >> 5);
            valid = (int)((p >> 4) & 1u);
            loc   = (int)(p & 15u);
            // sortL/permL reuse next level is separated by >=1 barrier (safe:
            // each wave only writes its own sortL column before the next barrier)
        }

        const int node = off + loc;     // wave-uniform after sort (boundary waves <=2 nodes)
        const float* xr = x + (size_t)id * NF;

        // Gather 16 subset features (the only scattered loads in the kernel)
        float xs[NK];
        const int* si = subset_idx + node * NK;
        #pragma unroll
        for (int k = 0; k < NK; ++k) xs[k] = xr[si[k]];

        // h1 = leaky(W1[node] @ xs + b1)   (32x16 GEMV, uniform-address float4)
        float h1v[NH];
        const float4* w1g = (const float4*)(W1 + node * (NH * NK));
        const float* b1g = b1 + node * NH;
        #pragma unroll
        for (int j = 0; j < NH; ++j) {
            float acc = b1g[j];
            #pragma unroll
            for (int q = 0; q < NK / 4; ++q) {
                const float4 t = w1g[j * 4 + q];
                acc += t.x * xs[q * 4 + 0];
                acc += t.y * xs[q * 4 + 1];
                acc += t.z * xs[q * 4 + 2];
                acc += t.w * xs[q * 4 + 3];
            }
            h1v[j] = (acc >= 0.f) ? acc : 0.01f * acc;
        }

        // h2 + logits FUSED: h2[g] is consumed by l0/l1 immediately and dies.
        // (eliminates the h2v[32] array -> peak live fits the 64-VGPR budget)
        const float4* w2g = (const float4*)(W2 + node * (NH * NH));
        const float* b2g = b2 + node * NH;
        const float* w3g = W3 + node * 2 * NH;
        float l0 = b3[node * 2 + 0];
        float l1 = b3[node * 2 + 1];
        #pragma unroll
        for (int g = 0; g < NH; ++g) {
            float acc = b2g[g];
            #pragma unroll
            for (int q = 0; q < NH / 4; ++q) {
                const float4 t = w2g[g * 8 + q];
                acc += t.x * h1v[q * 4 + 0];
                acc += t.y * h1v[q * 4 + 1];
                acc += t.z * h1v[q * 4 + 2];
                acc += t.w * h1v[q * 4 + 3];
            }
            const float h2 = (acc >= 0.f) ? acc : 0.01f * acc;
            l0 += w3g[g]      * h2;     // same g=0..31 order as before: bit-exact
            l1 += w3g[NH + g] * h2;
        }

        // p0 < 0.5  <=>  l0 < l1  (softmax is monotone)
        const int bit = (l0 < l1) ? 1 : 0;
        loc = 2 * loc + bit;
        off = 2 * off + 1;              // node offsets: 0, 1, 3, 7
    }

    if (valid) out[id] = leaf_best[loc];
}

extern "C" void kernel_launch(void* const* d_in, const int* in_sizes, int n_in,
                              void* d_out, int out_size, void* d_ws, size_t ws_size,
                              hipStream_t stream) {
    const float* x         = (const float*)d_in[0];
    const float* W1        = (const float*)d_in[1];
    const float* b1        = (const float*)d_in[2];
    const float* W2        = (const float*)d_in[3];
    const float* b2        = (const float*)d_in[4];
    const float* W3        = (const float*)d_in[5];
    const float* b3        = (const float*)d_in[6];
    const float* leaf_best = (const float*)d_in[7];
    const int*   subset    = (const int*)d_in[8];

    const int N = in_sizes[0] / NF;
    const int grid = (N + BLOCK - 1) / BLOCK;
    tree_mlp_kernel<<<grid, BLOCK, 0, stream>>>(
        x, W1, b1, W2, b2, W3, b3, leaf_best, subset, (float*)d_out, N);
}